// Round 3
// baseline (105.081 us; speedup 1.0000x reference)
//
#include <hip/hip_runtime.h>

#define GRIDN 256
#define NVOX (GRIDN * GRIDN * GRIDN)   // 16,777,216 voxels, 64 MiB fp32

// ---------------------------------------------------------------------------
// Fast fill: float4 grid-stride zero. rocclr's fillBuffer ran at 1.4 TB/s;
// this should stream writes at >5.5 TB/s.
// ---------------------------------------------------------------------------
__global__ __launch_bounds__(256) void k_zero4(float4* __restrict__ p, int n4) {
    int stride = gridDim.x * blockDim.x;
    float4 z = make_float4(0.f, 0.f, 0.f, 0.f);
    for (int i = blockIdx.x * blockDim.x + threadIdx.x; i < n4; i += stride)
        p[i] = z;
}

// ---------------------------------------------------------------------------
// Scatter: vol[d][h][w] += feats[i].
// ---------------------------------------------------------------------------
__global__ void k_scatter(const float* __restrict__ feats,
                          const int* __restrict__ coords,
                          float* __restrict__ vol, int n) {
    int i = blockIdx.x * blockDim.x + threadIdx.x;
    if (i >= n) return;
    int d = coords[3 * i + 0];
    int h = coords[3 * i + 1];
    int w = coords[3 * i + 2];
    atomicAdd(&vol[(d * GRIDN + h) * GRIDN + w], feats[i]);
}

// ---------------------------------------------------------------------------
// z-pass, float4-vectorized, XCD-bijective block swizzle.
// ---------------------------------------------------------------------------
__global__ __launch_bounds__(256) void k_zpass(const float4* __restrict__ in,
                                               float4* __restrict__ out) {
    const int nb  = gridDim.x;          // 16384, divisible by 8
    const int cpx = nb >> 3;
    int b  = blockIdx.x;
    int sb = (b & 7) * cpx + (b >> 3);
    int i  = sb * 256 + threadIdx.x;
    int d  = (i >> 14) & (GRIDN - 1);

    float4 s = in[i];
    if (d >= 1) { float4 a = in[i - 16384]; s.x += a.x; s.y += a.y; s.z += a.z; s.w += a.w; }
    if (d >= 2) { float4 a = in[i - 32768]; s.x += a.x; s.y += a.y; s.z += a.z; s.w += a.w; }
    if (d <= GRIDN - 2) { float4 a = in[i + 16384]; s.x += a.x; s.y += a.y; s.z += a.z; s.w += a.w; }
    if (d <= GRIDN - 3) { float4 a = in[i + 32768]; s.x += a.x; s.y += a.y; s.z += a.z; s.w += a.w; }
    out[i] = s;
}

// ---------------------------------------------------------------------------
// Fused y+x pass over one z-slice tile. Tile = 128(x) x 32(y) outputs.
// ---------------------------------------------------------------------------
#define TX 128
#define TY 32
__global__ __launch_bounds__(256) void k_xypass(const float* __restrict__ in,
                                                float* __restrict__ out) {
    __shared__ float R[36][132];
    __shared__ float Xp[36][128];
    const int x0  = blockIdx.x * TX;
    const int y0  = blockIdx.y * TY;
    const int z   = blockIdx.z;
    const int tid = threadIdx.x;
    const float* slice = in + (size_t)z * (GRIDN * GRIDN);

    for (int idx = tid; idx < 36 * 132; idx += 256) {
        int yy = idx / 132;
        int xx = idx - yy * 132;
        int gy = y0 + yy - 2;
        int gx = x0 + xx - 2;
        float v = 0.f;
        if ((unsigned)gy < GRIDN && (unsigned)gx < GRIDN)
            v = slice[gy * GRIDN + gx];
        R[yy][xx] = v;
    }
    __syncthreads();

    for (int idx = tid; idx < 36 * 128; idx += 256) {
        int yy = idx >> 7;
        int x  = idx & 127;
        Xp[yy][x] = R[yy][x] + R[yy][x + 1] + R[yy][x + 2] + R[yy][x + 3] + R[yy][x + 4];
    }
    __syncthreads();

    int x     = tid & 127;
    int yb    = tid >> 7;
    int ybase = yb * 16;
    float w0 = Xp[ybase + 0][x];
    float w1 = Xp[ybase + 1][x];
    float w2 = Xp[ybase + 2][x];
    float w3 = Xp[ybase + 3][x];
    float w4 = Xp[ybase + 4][x];
    float* op = out + (size_t)z * GRIDN * GRIDN + (size_t)(y0 + ybase) * GRIDN + (x0 + x);
    #pragma unroll
    for (int r = 0; r < 16; ++r) {
        *op = w0 + w1 + w2 + w3 + w4;
        op += GRIDN;
        w0 = w1; w1 = w2; w2 = w3; w3 = w4;
        if (r < 15) w4 = Xp[ybase + r + 5][x];
    }
}

// ---------------------------------------------------------------------------
// Fallback if ws is too small: direct 125-way atomic expansion.
// ---------------------------------------------------------------------------
__global__ void k_scatter125(const float* __restrict__ feats,
                             const int* __restrict__ coords,
                             float* __restrict__ out, int n) {
    int i = blockIdx.x * blockDim.x + threadIdx.x;
    if (i >= n) return;
    int d = coords[3 * i + 0];
    int h = coords[3 * i + 1];
    int w = coords[3 * i + 2];
    float f = feats[i];
    int d0 = max(d - 2, 0), d1 = min(d + 2, GRIDN - 1);
    int h0 = max(h - 2, 0), h1 = min(h + 2, GRIDN - 1);
    int w0 = max(w - 2, 0), w1 = min(w + 2, GRIDN - 1);
    for (int dd = d0; dd <= d1; ++dd)
        for (int hh = h0; hh <= h1; ++hh)
            for (int ww = w0; ww <= w1; ++ww)
                atomicAdd(&out[(dd * GRIDN + hh) * GRIDN + ww], f);
}

extern "C" void kernel_launch(void* const* d_in, const int* in_sizes, int n_in,
                              void* d_out, int out_size, void* d_ws, size_t ws_size,
                              hipStream_t stream) {
    const float* feats  = (const float*)d_in[0];
    const int*   coords = (const int*)d_in[1];
    float*       out    = (float*)d_out;
    int n = in_sizes[0];

    const size_t vol_bytes = (size_t)NVOX * sizeof(float);

    if (ws_size >= vol_bytes) {
        float* ws = (float*)d_ws;
        // 1. Zero d_out (custom float4 fill), scatter active voxels into it.
        k_zero4<<<2048, 256, 0, stream>>>((float4*)out, NVOX / 4);
        k_scatter<<<(n + 255) / 256, 256, 0, stream>>>(feats, coords, out, n);
        // 2. z-pass: out -> ws (float4, XCD-swizzled).
        k_zpass<<<NVOX / 4 / 256, 256, 0, stream>>>((const float4*)out, (float4*)ws);
        // 3. fused y+x pass: ws -> out.
        dim3 grid(GRIDN / TX, GRIDN / TY, GRIDN);
        k_xypass<<<grid, 256, 0, stream>>>(ws, out);
    } else {
        k_zero4<<<2048, 256, 0, stream>>>((float4*)out, NVOX / 4);
        k_scatter125<<<(n + 255) / 256, 256, 0, stream>>>(feats, coords, out, n);
    }
}

// Round 4
// 87.478 us; speedup vs baseline: 1.2012x; 1.2012x over previous
//
#include <hip/hip_runtime.h>

#define GRIDN 256
#define NVOX (GRIDN * GRIDN * GRIDN)   // 16,777,216 voxels, 64 MiB fp32

// ---------------------------------------------------------------------------
// Fast fill: float4 grid-stride zero (rocclr fill measured 1.4 TB/s).
// ---------------------------------------------------------------------------
__global__ __launch_bounds__(256) void k_zero4(float4* __restrict__ p, int n4) {
    int stride = gridDim.x * blockDim.x;
    float4 z = make_float4(0.f, 0.f, 0.f, 0.f);
    for (int i = blockIdx.x * blockDim.x + threadIdx.x; i < n4; i += stride)
        p[i] = z;
}

// ---------------------------------------------------------------------------
// Scatter: vol[d][h][w] += feats[i].
// ---------------------------------------------------------------------------
__global__ void k_scatter(const float* __restrict__ feats,
                          const int* __restrict__ coords,
                          float* __restrict__ vol, int n) {
    int i = blockIdx.x * blockDim.x + threadIdx.x;
    if (i >= n) return;
    int d = coords[3 * i + 0];
    int h = coords[3 * i + 1];
    int w = coords[3 * i + 2];
    atomicAdd(&vol[(d * GRIDN + h) * GRIDN + w], feats[i]);
}

// ---------------------------------------------------------------------------
// Fully fused 5x5x5 box conv: one read of the dense volume, one write of out.
// Block = 512 threads, owns a 64(x) x 32(y) tile, streams ZS=16 output slices
// (20 input slices incl. z-halo). Per input slice:
//   stage R[36][72] (xy tile + halo, float4, zero-padded)  -> bar
//   x-pass into Xp[36][64]                                 -> bar
//   y-pass: thread (xq=(t&15)*4, yy=t>>4) reads 5 float4 rows of Xp -> v
// 5-deep float4 register ring (static shift) accumulates the z window;
// out[z-2] written as one float4 per thread (fully coalesced 1KB/wave).
// ---------------------------------------------------------------------------
#define TXF 64
#define TYF 32
#define ZS  16
__global__ __launch_bounds__(512) void k_fused(const float* __restrict__ in,
                                               float* __restrict__ out) {
    __shared__ float R[36][72];    // rows y0-2..y0+33, cols x0-4..x0+67
    __shared__ float Xp[36][64];   // x-box-summed, cols x0..x0+63

    const int tid = threadIdx.x;
    const int x0  = blockIdx.x * TXF;
    const int y0  = blockIdx.y * TYF;
    const int z0  = blockIdx.z * ZS;
    const int xq  = (tid & 15) * 4;   // thread's 4 consecutive x
    const int yy  = tid >> 4;         // thread's y row, 0..31

    float4 a0 = {0,0,0,0}, a1 = {0,0,0,0}, a2 = {0,0,0,0},
           a3 = {0,0,0,0}, a4 = {0,0,0,0};

    for (int zi = z0 - 2; zi < z0 + ZS + 2; ++zi) {
        float4 v = {0,0,0,0};
        if ((unsigned)zi < (unsigned)GRIDN) {
            const float4* slice4 = (const float4*)(in + (size_t)zi * (GRIDN * GRIDN));
            // stage 36 rows x 18 float4 (zero-padded outside the volume)
            __syncthreads();   // protect previous iter's Xp reads before R/Xp rewrite
            for (int idx = tid; idx < 36 * 18; idx += 512) {
                int row = idx / 18;
                int c4  = idx - row * 18;
                int gy  = y0 + row - 2;
                int gx4 = (x0 >> 2) - 1 + c4;
                float4 val = {0,0,0,0};
                if ((unsigned)gy < (unsigned)GRIDN && (unsigned)gx4 < (unsigned)(GRIDN / 4))
                    val = slice4[gy * (GRIDN / 4) + gx4];
                *(float4*)&R[row][c4 * 4] = val;
            }
            __syncthreads();
            // x-pass
            for (int idx = tid; idx < 36 * 64; idx += 512) {
                int row = idx >> 6;
                int xc  = idx & 63;
                Xp[row][xc] = R[row][xc + 2] + R[row][xc + 3] + R[row][xc + 4]
                            + R[row][xc + 5] + R[row][xc + 6];
            }
            __syncthreads();
            // y-pass: 5 float4 rows
            float4 r0 = *(const float4*)&Xp[yy + 0][xq];
            float4 r1 = *(const float4*)&Xp[yy + 1][xq];
            float4 r2 = *(const float4*)&Xp[yy + 2][xq];
            float4 r3 = *(const float4*)&Xp[yy + 3][xq];
            float4 r4 = *(const float4*)&Xp[yy + 4][xq];
            v.x = r0.x + r1.x + r2.x + r3.x + r4.x;
            v.y = r0.y + r1.y + r2.y + r3.y + r4.y;
            v.z = r0.z + r1.z + r2.z + r3.z + r4.z;
            v.w = r0.w + r1.w + r2.w + r3.w + r4.w;
        }
        // shift z-ring (static indices only)
        a0 = a1; a1 = a2; a2 = a3; a3 = a4; a4 = v;
        int zo = zi - 2;
        if (zo >= z0) {   // upper bound implicit (zo < z0+ZS since zi < z0+ZS+2)
            float4 s;
            s.x = a0.x + a1.x + a2.x + a3.x + a4.x;
            s.y = a0.y + a1.y + a2.y + a3.y + a4.y;
            s.z = a0.z + a1.z + a2.z + a3.z + a4.z;
            s.w = a0.w + a1.w + a2.w + a3.w + a4.w;
            float4* op = (float4*)(out + (size_t)zo * (GRIDN * GRIDN)
                                       + (size_t)(y0 + yy) * GRIDN + x0 + xq);
            *op = s;
        }
    }
}

// ---------------------------------------------------------------------------
// Fallback if ws is too small: direct 125-way atomic expansion.
// ---------------------------------------------------------------------------
__global__ void k_scatter125(const float* __restrict__ feats,
                             const int* __restrict__ coords,
                             float* __restrict__ out, int n) {
    int i = blockIdx.x * blockDim.x + threadIdx.x;
    if (i >= n) return;
    int d = coords[3 * i + 0];
    int h = coords[3 * i + 1];
    int w = coords[3 * i + 2];
    float f = feats[i];
    int d0 = max(d - 2, 0), d1 = min(d + 2, GRIDN - 1);
    int h0 = max(h - 2, 0), h1 = min(h + 2, GRIDN - 1);
    int w0 = max(w - 2, 0), w1 = min(w + 2, GRIDN - 1);
    for (int dd = d0; dd <= d1; ++dd)
        for (int hh = h0; hh <= h1; ++hh)
            for (int ww = w0; ww <= w1; ++ww)
                atomicAdd(&out[(dd * GRIDN + hh) * GRIDN + ww], f);
}

extern "C" void kernel_launch(void* const* d_in, const int* in_sizes, int n_in,
                              void* d_out, int out_size, void* d_ws, size_t ws_size,
                              hipStream_t stream) {
    const float* feats  = (const float*)d_in[0];
    const int*   coords = (const int*)d_in[1];
    float*       out    = (float*)d_out;
    int n = in_sizes[0];

    const size_t vol_bytes = (size_t)NVOX * sizeof(float);

    if (ws_size >= vol_bytes) {
        float* ws = (float*)d_ws;
        // 1. Zero ws, scatter active voxels into it.
        k_zero4<<<2048, 256, 0, stream>>>((float4*)ws, NVOX / 4);
        k_scatter<<<(n + 255) / 256, 256, 0, stream>>>(feats, coords, ws, n);
        // 2. Single fused x+y+z box pass: ws -> out.
        dim3 grid(GRIDN / TXF, GRIDN / TYF, GRIDN / ZS);
        k_fused<<<grid, 512, 0, stream>>>(ws, out);
    } else {
        k_zero4<<<2048, 256, 0, stream>>>((float4*)out, NVOX / 4);
        k_scatter125<<<(n + 255) / 256, 256, 0, stream>>>(feats, coords, out, n);
    }
}